// Round 12
// baseline (4168.826 us; speedup 1.0000x reference)
//
#include <hip/hip_runtime.h>

#define TSTEPS  2048
#define DIN     64
#define UNITS   128
#define UNFOLDS 6
#define NT      128

// 2-wave minimum-latency config (R8 structure, R7 precision profile).
// Lane L: p=L&3 (K-chunk [32p,32p+32)), G=L>>2 (units 4G..4G+3).
// Per sub-step: 4x ds_read_b128 (h packed f16 at words [16p,16p+16) --
// R8/R9/R10 read [8p,...): THE bug, now fixed), 64 dot2, 2-stage quad_perm
// reduce-scatter (lane ends owning unit 4G+p), nonlin once, even-p lanes
// pack (own, xor1-neighbor) h via RNE casts -> one b32 publish. ONE raw
// s_barrier per sub-step. f16 ONLY on W and h (RNE, R7-proven 2e-3);
// x-projection exact fp32 (resident fp32 kern frags, once per t).

typedef _Float16 h16x2 __attribute__((ext_vector_type(2)));

template <int CTRL>
__device__ __forceinline__ float dpp_f(float v) {
    return __int_as_float(
        __builtin_amdgcn_mov_dpp(__float_as_int(v), CTRL, 0xF, 0xF, true));
}

// RNE pack: {f16(a) low, f16(b) high}
__device__ __forceinline__ unsigned pack_rne(float a, float b) {
    unsigned short ua = __builtin_bit_cast(unsigned short, (_Float16)a);
    unsigned short ub = __builtin_bit_cast(unsigned short, (_Float16)b);
    return (unsigned)ua | ((unsigned)ub << 16);
}

__device__ __forceinline__ float dot2(h16x2 a, h16x2 b, float c) {
#if __has_builtin(__builtin_amdgcn_fdot2)
    return __builtin_amdgcn_fdot2(a, b, c, false);
#else
    return fmaf((float)a.x, (float)b.x, fmaf((float)a.y, (float)b.y, c));
#endif
}

__global__ __launch_bounds__(NT) void ltc_kernel(
    const float* __restrict__ x,      // [B,T,DIN]
    const float* __restrict__ kern,   // [DIN,UNITS]
    const float* __restrict__ rk,     // [UNITS,UNITS]
    const float* __restrict__ bias,   // [UNITS]
    const float* __restrict__ tau,    // [UNITS]
    const float* __restrict__ Avec,   // [UNITS]
    const float* __restrict__ okern,  // [UNITS,1]
    const float* __restrict__ obias,  // [1]
    float* __restrict__ out)          // [B,T,1]
{
    const int b    = blockIdx.x;
    const int tid  = threadIdx.x;
    const int p    = tid & 3;       // K-quadrant
    const int G    = tid >> 2;      // unit group: units 4G..4G+3 (G in [0,32))
    const int wv   = tid >> 6;
    const int lane = tid & 63;

    __shared__ __align__(16) unsigned hbuf[2][UNITS / 2];  // h as packed f16x2
    __shared__ float part[2];

    // resident recurrent weights, f16 K-pairs (RNE casts):
    // w2_[m][j] = ( rk[32p+2m][4G+j], rk[32p+2m+1][4G+j] ), m in [0,16)
    h16x2 w2_[16][4];
    #pragma unroll
    for (int m = 0; m < 16; ++m) {
        const float* r0 = rk + (size_t)(32 * p + 2 * m) * UNITS + 4 * G;
        const float* r1 = r0 + UNITS;
        #pragma unroll
        for (int j = 0; j < 4; ++j) {
            h16x2 v; v.x = (_Float16)r0[j]; v.y = (_Float16)r1[j];
            w2_[m][j] = v;
        }
    }
    // resident input kernel, fp32: kk_[m][j] = kern[16p+m][4G+j], m in [0,16)
    float kk_[16][4];
    #pragma unroll
    for (int m = 0; m < 16; ++m) {
        const float* r0 = kern + (size_t)(16 * p + m) * UNITS + 4 * G;
        #pragma unroll
        for (int j = 0; j < 4; ++j) kk_[m][j] = r0[j];
    }

    // constants for owned unit u_own = 4G + p
    const int   u_own = 4 * G + p;
    const float dt    = 1.0f / 6.0f;
    const float dtA_o  = dt * Avec[u_own];
    const float cden_o = 1.0f + dt / tau[u_own];
    const float cdp_o  = cden_o + dt;
    const float ok_o   = okern[u_own];
    float bias4[4];
    #pragma unroll
    for (int j = 0; j < 4; ++j) bias4[j] = (p == 0) ? bias[4 * G + j] : 0.0f;
    const float ob = obias[0];

    float h_own = 0.0f;
    if (tid < UNITS / 2) { hbuf[0][tid] = 0u; hbuf[1][tid] = 0u; }

    const float* xb = x + (size_t)b * TSTEPS * DIN;
    float4 xr[4];
    #pragma unroll
    for (int m = 0; m < 4; ++m) xr[m] = *(const float4*)(xb + 16 * p + 4 * m);
    __syncthreads();

    for (int t = 0; t < TSTEPS; ++t) {
        // x-projection partial, exact fp32 (valid all 6 sub-steps)
        float xp[4] = {bias4[0], bias4[1], bias4[2], bias4[3]};
        {
            float xq[16];
            #pragma unroll
            for (int m = 0; m < 4; ++m) {
                xq[4 * m + 0] = xr[m].x; xq[4 * m + 1] = xr[m].y;
                xq[4 * m + 2] = xr[m].z; xq[4 * m + 3] = xr[m].w;
            }
            #pragma unroll
            for (int m = 0; m < 16; ++m)
                #pragma unroll
                for (int j = 0; j < 4; ++j)
                    xp[j] = fmaf(xq[m], kk_[m][j], xp[j]);
        }

        // prefetch next x row (raw barriers keep it in flight)
        int tn = (t + 1 < TSTEPS) ? t + 1 : t;
        float4 xn[4];
        #pragma unroll
        for (int m = 0; m < 4; ++m)
            xn[m] = *(const float4*)(xb + (size_t)tn * DIN + 16 * p + 4 * m);

        #pragma unroll
        for (int s = 0; s < UNFOLDS; ++s) {
            // this quadrant's 32 h values: words [16p,16p+16), 4x b128
            h16x2 hh[16];
            {
                const uint4* hv = (const uint4*)&hbuf[s & 1][16 * p];
                *(uint4*)&hh[0]  = hv[0];
                *(uint4*)&hh[4]  = hv[1];
                *(uint4*)&hh[8]  = hv[2];
                *(uint4*)&hh[12] = hv[3];
            }

            float acc[4] = {xp[0], xp[1], xp[2], xp[3]};
            float accB[4] = {0.f, 0.f, 0.f, 0.f};
            #pragma unroll
            for (int m = 0; m < 8; ++m)
                #pragma unroll
                for (int j = 0; j < 4; ++j)
                    acc[j] = dot2(hh[m], w2_[m][j], acc[j]);
            #pragma unroll
            for (int m = 8; m < 16; ++m)
                #pragma unroll
                for (int j = 0; j < 4; ++j)
                    accB[j] = dot2(hh[m], w2_[m][j], accB[j]);
            #pragma unroll
            for (int j = 0; j < 4; ++j) acc[j] += accB[j];

            // 2-stage quad reduce-scatter: lane ends owning unit 4G+p
            const bool b0 = (p & 1) != 0;
            const bool b1 = (p & 2) != 0;
            float k0 = b0 ? acc[1] : acc[0];
            float s0 = b0 ? acc[0] : acc[1];
            float k1 = b0 ? acc[3] : acc[2];
            float s1 = b0 ? acc[2] : acc[3];
            float r0 = k0 + dpp_f<0xB1>(s0);   // units 4G+bit0, 4G+2+bit0
            float r1 = k1 + dpp_f<0xB1>(s1);
            float k2 = b1 ? r1 : r0;
            float s2 = b1 ? r0 : r1;
            float sv = k2 + dpp_f<0x4E>(s2);   // unit 4G+p

            // gating + semi-implicit Euler, once per lane
            float e   = __expf(-sv);                    // f = 1/(1+e)
            float num = fmaf(h_own, e, h_own + dtA_o);
            float den = fmaf(cden_o, e, cdp_o);
            h_own = num * __builtin_amdgcn_rcpf(den);

            // publish: even-p lane packs (own, xor1-neighbor), RNE -> one b32
            float hN = dpp_f<0xB1>(h_own);
            if ((p & 1) == 0)
                hbuf[(s & 1) ^ 1][2 * G + (p >> 1)] = pack_rne(h_own, hN);

            if (s == UNFOLDS - 1) {
                float q = h_own * ok_o;
                q += __shfl_xor(q, 1);
                q += __shfl_xor(q, 2);
                q += __shfl_xor(q, 4);
                q += __shfl_xor(q, 8);
                q += __shfl_xor(q, 16);
                q += __shfl_xor(q, 32);
                if (lane == 0) part[wv] = q;
            }

            asm volatile("s_waitcnt lgkmcnt(0)" ::: "memory");
            __builtin_amdgcn_sched_barrier(0);
            __builtin_amdgcn_s_barrier();
            __builtin_amdgcn_sched_barrier(0);
        }

        if (tid == 0)
            out[(size_t)b * TSTEPS + t] = part[0] + part[1] + ob;

        #pragma unroll
        for (int m = 0; m < 4; ++m) xr[m] = xn[m];
    }
}

extern "C" void kernel_launch(void* const* d_in, const int* in_sizes, int n_in,
                              void* d_out, int out_size, void* d_ws, size_t ws_size,
                              hipStream_t stream) {
    const float* x     = (const float*)d_in[0];
    const float* kern  = (const float*)d_in[1];
    const float* rk    = (const float*)d_in[2];
    const float* bias  = (const float*)d_in[3];
    const float* tau   = (const float*)d_in[4];
    const float* Avec  = (const float*)d_in[5];
    const float* okern = (const float*)d_in[6];
    const float* obias = (const float*)d_in[7];
    float* out = (float*)d_out;

    ltc_kernel<<<64, NT, 0, stream>>>(
        x, kern, rk, bias, tau, Avec, okern, obias, out);
}